// Round 1
// baseline (200.608 us; speedup 1.0000x reference)
//
#include <hip/hip_runtime.h>
#include <stdint.h>

// MultiHeadSelfAttention: x[2,2048,1024] fp32, w_qkv[1024,3072], w_proj[1024,1024], b_proj[1024]
// Pipeline: cvt/transpose -> GEMM1(qkv, bf16 MFMA) -> transpose V -> flash attention -> GEMM2(+bias)
// ws usage: 58,720,256 bytes.

typedef unsigned short u16;
typedef __bf16 bf16x8 __attribute__((ext_vector_type(8)));
typedef unsigned short u16x8 __attribute__((ext_vector_type(8)));
typedef float f32x4 __attribute__((ext_vector_type(4)));

#define DEV static __device__ __forceinline__

DEV u16 f2bf(float f) {
    uint32_t u = __float_as_uint(f);
    u += 0x7fffu + ((u >> 16) & 1u);
    return (u16)(u >> 16);
}

// All LDS tiles are [rows][64] bf16 (128 B rows). XOR swizzle spreads the 16B
// chunks of a row across banks: byte ^= (row&7)<<4.
DEV void swz_store16(u16* base, int row, int col16, u16x8 v) {
    int off = (row * 128 + col16 * 16) ^ ((row & 7) << 4);
    *reinterpret_cast<u16x8*>(reinterpret_cast<char*>(base) + off) = v;
}
DEV bf16x8 swz_load16(const u16* base, int row, int kbyte) {
    int off = (row * 128 + kbyte) ^ ((row & 7) << 4);
    return *reinterpret_cast<const bf16x8*>(reinterpret_cast<const char*>(base) + off);
}

// ---------------- conversion kernels ----------------

__global__ void cvt_x_kernel(const float* __restrict__ in, u16* __restrict__ out) {
    int t = blockIdx.x * 256 + threadIdx.x;  // 524288 threads, 8 floats each
    const float4* p = reinterpret_cast<const float4*>(in) + (size_t)t * 2;
    float4 a = p[0], b = p[1];
    u16x8 o;
    o[0] = f2bf(a.x); o[1] = f2bf(a.y); o[2] = f2bf(a.z); o[3] = f2bf(a.w);
    o[4] = f2bf(b.x); o[5] = f2bf(b.y); o[6] = f2bf(b.z); o[7] = f2bf(b.w);
    reinterpret_cast<u16x8*>(out)[t] = o;
}

// transpose fp32 [R][Cc] -> bf16 [Cc][R]
__global__ void trw_kernel(const float* __restrict__ in, u16* __restrict__ out, int R, int Cc) {
    __shared__ float T[32][33];
    int x = blockIdx.x * 32 + threadIdx.x;
    int y0 = blockIdx.y * 32;
#pragma unroll
    for (int i = 0; i < 4; i++) {
        int y = y0 + threadIdx.y + i * 8;
        T[threadIdx.y + i * 8][threadIdx.x] = in[(size_t)y * Cc + x];
    }
    __syncthreads();
    int xo = y0 + threadIdx.x;
    int yo0 = blockIdx.x * 32;
#pragma unroll
    for (int i = 0; i < 4; i++) {
        int yo = yo0 + threadIdx.y + i * 8;
        out[(size_t)yo * R + xo] = f2bf(T[threadIdx.x][threadIdx.y + i * 8]);
    }
}

// transpose bf16 v[bh][2048][64] -> vt[bh][64][2048]
__global__ void trv_kernel(const u16* __restrict__ v, u16* __restrict__ vt) {
    __shared__ u16 T[64][72];
    int bh = blockIdx.y, t = blockIdx.x, tid = threadIdx.x;
    const u16* vb = v + (size_t)bh * 2048 * 64;
    u16* vo = vt + (size_t)bh * 64 * 2048;
#pragma unroll
    for (int i = 0; i < 2; i++) {
        int c = tid + i * 256, row = c >> 3, c8 = c & 7;
        u16x8 a = *reinterpret_cast<const u16x8*>(vb + (size_t)(t * 64 + row) * 64 + c8 * 8);
#pragma unroll
        for (int j = 0; j < 8; j++) T[row][c8 * 8 + j] = a[j];
    }
    __syncthreads();
#pragma unroll
    for (int i = 0; i < 2; i++) {
        int c = tid + i * 256, drow = c >> 3, c8 = c & 7;
        u16x8 o;
#pragma unroll
        for (int j = 0; j < 8; j++) o[j] = T[c8 * 8 + j][drow];
        *reinterpret_cast<u16x8*>(vo + (size_t)drow * 2048 + t * 64 + c8 * 8) = o;
    }
}

// ---------------- GEMM: A[M,1024] bf16 row-major x Bt[N,1024] bf16 row-major ----------------
// 128x128 tile, BK=64, 4 waves each 64x64. EPI=0: scatter q(k,v) bf16; EPI=1: fp32 out + bias.

template <int EPI>
__global__ __launch_bounds__(256, 2) void gemm_kernel(
    const u16* __restrict__ A, const u16* __restrict__ Bt, int ntiles,
    u16* __restrict__ o_q, u16* __restrict__ o_k, u16* __restrict__ o_v,
    float* __restrict__ o_f, const float* __restrict__ bias) {
    __shared__ __align__(16) u16 Al[128 * 64];
    __shared__ __align__(16) u16 Bl[128 * 64];
    int tid = threadIdx.x;
    int bm = blockIdx.x / ntiles, bn = blockIdx.x % ntiles;
    int lane = tid & 63, w = tid >> 6;
    int wr = w >> 1, wc = w & 1;
    int l15 = lane & 15, lhi = lane >> 4;
    const int K = 1024;

    f32x4 acc[4][4];
#pragma unroll
    for (int i = 0; i < 4; i++)
#pragma unroll
        for (int j = 0; j < 4; j++) acc[i][j] = (f32x4){0.f, 0.f, 0.f, 0.f};

    for (int kt = 0; kt < 16; ++kt) {
#pragma unroll
        for (int i = 0; i < 4; i++) {
            int c = tid + i * 256;
            int row = c >> 3, c16 = c & 7;
            u16x8 av = *reinterpret_cast<const u16x8*>(A + (size_t)(bm * 128 + row) * K + kt * 64 + c16 * 8);
            u16x8 bv = *reinterpret_cast<const u16x8*>(Bt + (size_t)(bn * 128 + row) * K + kt * 64 + c16 * 8);
            swz_store16(Al, row, c16, av);
            swz_store16(Bl, row, c16, bv);
        }
        __syncthreads();
#pragma unroll
        for (int ks = 0; ks < 2; ++ks) {
            bf16x8 af[4], bfr[4];
#pragma unroll
            for (int mi = 0; mi < 4; ++mi) af[mi] = swz_load16(Al, wr * 64 + mi * 16 + l15, ks * 64 + lhi * 16);
#pragma unroll
            for (int ni = 0; ni < 4; ++ni) bfr[ni] = swz_load16(Bl, wc * 64 + ni * 16 + l15, ks * 64 + lhi * 16);
#pragma unroll
            for (int mi = 0; mi < 4; ++mi)
#pragma unroll
                for (int ni = 0; ni < 4; ++ni)
                    acc[mi][ni] = __builtin_amdgcn_mfma_f32_16x16x32_bf16(af[mi], bfr[ni], acc[mi][ni], 0, 0, 0);
        }
        __syncthreads();
    }

    int row0 = bm * 128 + wr * 64, col0 = bn * 128 + wc * 64;
    if (EPI == 0) {
#pragma unroll
        for (int mi = 0; mi < 4; mi++)
#pragma unroll
            for (int ni = 0; ni < 4; ni++) {
                int col = col0 + ni * 16 + l15;
                int sel = col >> 10, cc = col & 1023;
                int h = cc >> 6, d = cc & 63;
#pragma unroll
                for (int j = 0; j < 4; j++) {
                    int r = row0 + mi * 16 + lhi * 4 + j;
                    int b = r >> 11, n = r & 2047;
                    size_t idx = (((size_t)(b * 16 + h)) * 2048 + n) * 64 + d;
                    float v = acc[mi][ni][j];
                    if (sel == 0) o_q[idx] = f2bf(v * 0.125f);   // fold softmax scale (exact pow2)
                    else if (sel == 1) o_k[idx] = f2bf(v);
                    else o_v[idx] = f2bf(v);
                }
            }
    } else {
#pragma unroll
        for (int mi = 0; mi < 4; mi++)
#pragma unroll
            for (int ni = 0; ni < 4; ni++) {
                int col = col0 + ni * 16 + l15;
                float bb = bias[col];
#pragma unroll
                for (int j = 0; j < 4; j++) {
                    int r = row0 + mi * 16 + lhi * 4 + j;
                    o_f[(size_t)r * 1024 + col] = acc[mi][ni][j] + bb;
                }
            }
    }
}

// ---------------- flash attention ----------------
// grid (32 q-tiles, 32 bh), 256 threads = 4 waves, each wave 16 q-rows, KVBLK=64.
__global__ __launch_bounds__(256, 2) void flash_kernel(
    const u16* __restrict__ q, const u16* __restrict__ k, const u16* __restrict__ vt,
    u16* __restrict__ o) {
    __shared__ __align__(16) u16 Kl[64 * 64];
    __shared__ __align__(16) u16 Vl[64 * 64];
    __shared__ __align__(16) u16 Pl[4][16 * 64];
    int tid = threadIdx.x, lane = tid & 63, w = tid >> 6;
    int l15 = lane & 15, lhi = lane >> 4;
    int bh = blockIdx.y, q0 = blockIdx.x * 64;

    const u16* qb = q + ((size_t)bh * 2048 + q0 + w * 16 + l15) * 64;
    bf16x8 qa[2];
    qa[0] = __builtin_bit_cast(bf16x8, *reinterpret_cast<const u16x8*>(qb + lhi * 8));
    qa[1] = __builtin_bit_cast(bf16x8, *reinterpret_cast<const u16x8*>(qb + 32 + lhi * 8));
    const u16* kb = k + (size_t)bh * 2048 * 64;
    const u16* vb = vt + (size_t)bh * 64 * 2048;

    f32x4 accO[4];
#pragma unroll
    for (int nf = 0; nf < 4; nf++) accO[nf] = (f32x4){0.f, 0.f, 0.f, 0.f};
    float m[4], lsum[4];
#pragma unroll
    for (int r = 0; r < 4; r++) { m[r] = -1e30f; lsum[r] = 0.f; }

    for (int t = 0; t < 32; t++) {
#pragma unroll
        for (int i = 0; i < 2; i++) {
            int c = tid + i * 256, row = c >> 3, c8 = c & 7;
            u16x8 kv8 = *reinterpret_cast<const u16x8*>(kb + (size_t)(t * 64 + row) * 64 + c8 * 8);
            u16x8 vv8 = *reinterpret_cast<const u16x8*>(vb + (size_t)row * 2048 + t * 64 + c8 * 8);
            swz_store16(Kl, row, c8, kv8);
            swz_store16(Vl, row, c8, vv8);
        }
        __syncthreads();

        f32x4 s[4];
#pragma unroll
        for (int nf = 0; nf < 4; nf++) {
            s[nf] = (f32x4){0.f, 0.f, 0.f, 0.f};
#pragma unroll
            for (int ks = 0; ks < 2; ks++)
                s[nf] = __builtin_amdgcn_mfma_f32_16x16x32_bf16(
                    qa[ks], swz_load16(Kl, nf * 16 + l15, ks * 64 + lhi * 16), s[nf], 0, 0, 0);
        }
        // online softmax (rows r_abs = lhi*4+r, cols spread over l15 x nf)
        float mx[4];
#pragma unroll
        for (int r = 0; r < 4; r++) mx[r] = fmaxf(fmaxf(s[0][r], s[1][r]), fmaxf(s[2][r], s[3][r]));
#pragma unroll
        for (int off = 1; off < 16; off <<= 1)
#pragma unroll
            for (int r = 0; r < 4; r++) mx[r] = fmaxf(mx[r], __shfl_xor(mx[r], off));
        float al[4], rs[4];
#pragma unroll
        for (int r = 0; r < 4; r++) {
            float mn = fmaxf(m[r], mx[r]);
            al[r] = __expf(m[r] - mn);
            m[r] = mn;
        }
#pragma unroll
        for (int nf = 0; nf < 4; nf++)
#pragma unroll
            for (int r = 0; r < 4; r++) s[nf][r] = __expf(s[nf][r] - m[r]);
#pragma unroll
        for (int r = 0; r < 4; r++) rs[r] = s[0][r] + s[1][r] + s[2][r] + s[3][r];
#pragma unroll
        for (int off = 1; off < 16; off <<= 1)
#pragma unroll
            for (int r = 0; r < 4; r++) rs[r] += __shfl_xor(rs[r], off);
#pragma unroll
        for (int r = 0; r < 4; r++) lsum[r] = lsum[r] * al[r] + rs[r];
#pragma unroll
        for (int nf = 0; nf < 4; nf++)
#pragma unroll
            for (int r = 0; r < 4; r++) accO[nf][r] *= al[r];

        // P (C-layout) -> LDS -> A-frag layout
        u16* Pw = Pl[w];
#pragma unroll
        for (int nf = 0; nf < 4; nf++)
#pragma unroll
            for (int r = 0; r < 4; r++) {
                int row = lhi * 4 + r;
                int off = (row * 128 + (nf * 16 + l15) * 2) ^ ((row & 7) << 4);
                *reinterpret_cast<u16*>(reinterpret_cast<char*>(Pw) + off) = f2bf(s[nf][r]);
            }
        bf16x8 pf0 = swz_load16(Pw, l15, lhi * 16);
        bf16x8 pf1 = swz_load16(Pw, l15, 64 + lhi * 16);
#pragma unroll
        for (int nf = 0; nf < 4; nf++) {
            accO[nf] = __builtin_amdgcn_mfma_f32_16x16x32_bf16(
                pf0, swz_load16(Vl, nf * 16 + l15, lhi * 16), accO[nf], 0, 0, 0);
            accO[nf] = __builtin_amdgcn_mfma_f32_16x16x32_bf16(
                pf1, swz_load16(Vl, nf * 16 + l15, 64 + lhi * 16), accO[nf], 0, 0, 0);
        }
        __syncthreads();
    }

    int b = bh >> 4, h = bh & 15;
#pragma unroll
    for (int r = 0; r < 4; r++) {
        float inv = 1.f / lsum[r];
        int qrow = q0 + w * 16 + lhi * 4 + r;
#pragma unroll
        for (int nf = 0; nf < 4; nf++) {
            int d = nf * 16 + l15;
            o[(((size_t)b * 2048 + qrow) * 16 + h) * 64 + d] = f2bf(accO[nf][r] * inv);
        }
    }
}

// ---------------- launch ----------------

extern "C" void kernel_launch(void* const* d_in, const int* in_sizes, int n_in,
                              void* d_out, int out_size, void* d_ws, size_t ws_size,
                              hipStream_t stream) {
    (void)in_sizes; (void)n_in; (void)out_size; (void)ws_size;
    const float* x = (const float*)d_in[0];
    const float* w_qkv = (const float*)d_in[1];
    const float* w_proj = (const float*)d_in[2];
    const float* b_proj = (const float*)d_in[3];
    float* out = (float*)d_out;
    char* ws = (char*)d_ws;

    u16* xb   = (u16*)(ws + 0);            // 4096x1024 bf16     (8,388,608 B)
    u16* wqt  = (u16*)(ws + 8388608);      // 3072x1024 bf16     (6,291,456 B)
    u16* wpt  = (u16*)(ws + 14680064);     // 1024x1024 bf16     (2,097,152 B)
    u16* qws  = (u16*)(ws + 16777216);     // [32][2048][64] bf16 (8,388,608 B)
    u16* kws  = (u16*)(ws + 25165824);
    u16* vws  = (u16*)(ws + 33554432);
    u16* vtws = (u16*)(ws + 41943040);     // [32][64][2048] bf16
    u16* attn = (u16*)(ws + 50331648);     // [4096][1024] bf16

    cvt_x_kernel<<<2048, 256, 0, stream>>>(x, xb);
    trw_kernel<<<dim3(96, 32), dim3(32, 8), 0, stream>>>(w_qkv, wqt, 1024, 3072);
    trw_kernel<<<dim3(32, 32), dim3(32, 8), 0, stream>>>(w_proj, wpt, 1024, 1024);
    gemm_kernel<0><<<32 * 24, 256, 0, stream>>>(xb, wqt, 24, qws, kws, vws, nullptr, nullptr);
    trv_kernel<<<dim3(32, 32), 256, 0, stream>>>(vws, vtws);
    flash_kernel<<<dim3(32, 32), 256, 0, stream>>>(qws, kws, vtws, attn);
    gemm_kernel<1><<<32 * 8, 256, 0, stream>>>(attn, wpt, 8, nullptr, nullptr, nullptr, out, b_proj);
}